// Round 16
// baseline (810.734 us; speedup 1.0000x reference)
//
#include <hip/hip_runtime.h>
#include <stdint.h>

#define NB 4
#define NN 8192
#define KNB 30
#define TOT (NB * NN)

// ---------------- threefry2x32 (JAX-exact, key = [0, 42]) ----------------
__device__ __forceinline__ uint32_t rotl32(uint32_t v, int r) {
    return (v << r) | (v >> (32 - r));
}

__device__ __forceinline__ void threefry(uint32_t x0, uint32_t x1,
                                         uint32_t& o0, uint32_t& o1) {
    const uint32_t ks0 = 0u, ks1 = 42u, ks2 = 0u ^ 42u ^ 0x1BD11BDAu;
    x0 += ks0; x1 += ks1;
#define RND(r) { x0 += x1; x1 = rotl32(x1, r); x1 ^= x0; }
    RND(13) RND(15) RND(26) RND(6)
    x0 += ks1; x1 += ks2 + 1u;
    RND(17) RND(29) RND(16) RND(24)
    x0 += ks2; x1 += ks0 + 2u;
    RND(13) RND(15) RND(26) RND(6)
    x0 += ks0; x1 += ks1 + 3u;
    RND(17) RND(29) RND(16) RND(24)
    x0 += ks1; x1 += ks2 + 4u;
    RND(13) RND(15) RND(26) RND(6)
    x0 += ks2; x1 += ks0 + 5u;
#undef RND
    o0 = x0; o1 = x1;
}

// ---- prep: SoA transpose w/ inf-baking (invalid coords -> +inf) -------------
__global__ void prep_kernel(const float* __restrict__ X,
                            const int* __restrict__ C,
                            float* __restrict__ Xs) {
    int t = blockIdx.x * blockDim.x + threadIdx.x;
    if (t >= TOT) return;
    const int b = t >> 13, n = t & (NN - 1);
    const bool valid = C[t] > 0;
    const float INF = __uint_as_float(0x7F800000u);
    const float* src = X + (size_t)t * 3;
    float* dst = Xs + (size_t)b * 3 * NN;
    dst[0 * NN + n] = valid ? src[0] : INF;
    dst[1 * NN + n] = valid ? src[1] : INF;
    dst[2 * NN + n] = valid ? src[2] : INF;
}

// ---------------- kNN: windowed single-level radix-select --------------------
// (R15-proven structure; collect rewritten as wave-aggregated ballot compact)
__global__ __launch_bounds__(256) void knn_kernel(const float* __restrict__ Xs,
                                                  const float* __restrict__ X,
                                                  int* __restrict__ edgesT) {
    const int row = blockIdx.x;          // 0..TOT-1 (block per row)
    const int b = row >> 13;
    const int i = row & (NN - 1);
    const float* Xsb = Xs + (size_t)b * 3 * NN;
    const float xi = X[(size_t)b * NN * 3 + i * 3 + 0];
    const float yi = X[(size_t)b * NN * 3 + i * 3 + 1];
    const float zi = X[(size_t)b * NN * 3 + i * 3 + 2];
    const int t = threadIdx.x;
    const uint32_t BIGBITS = __float_as_uint(1e9f);

    float d[32];
#pragma unroll
    for (int g = 0; g < 8; ++g) {
        const int j0 = g * 1024 + t * 4;
        const float4 x4 = *(const float4*)(Xsb + 0 * NN + j0);
        const float4 y4 = *(const float4*)(Xsb + 1 * NN + j0);
        const float4 z4 = *(const float4*)(Xsb + 2 * NN + j0);
#define D2(q, xx, yy, zz)                                                      \
        {                                                                      \
            float dx = __fsub_rn(xi, (xx));                                    \
            float dy = __fsub_rn(yi, (yy));                                    \
            float dz = __fsub_rn(zi, (zz));                                    \
            float d2 = __fadd_rn(__fadd_rn(__fmul_rn(dx, dx),                  \
                                           __fmul_rn(dy, dy)),                 \
                                 __fmul_rn(dz, dz));                           \
            d2 = __fadd_rn(d2, ((j0 + (q)) == i) ? 1e9f : 0.0f);               \
            d[g * 4 + (q)] = d2;                                               \
        }
        D2(0, x4.x, y4.x, z4.x)
        D2(1, x4.y, y4.y, z4.y)
        D2(2, x4.z, y4.z, z4.z)
        D2(3, x4.w, y4.w, z4.w)
#undef D2
    }

#define MKKEY(s) ((((unsigned long long)__float_as_uint(d[(s)])) << 32) | \
                  (unsigned)((((s) >> 2) * 1024) + t * 4 + ((s) & 3)))

    __shared__ uint32_t hist[16][257];   // 16 copies; +1 pad: 257 % 32 == 1
    __shared__ uint32_t colrow[256];
    __shared__ float wmin[4];
    __shared__ unsigned long long cbuf[64];
    __shared__ uint32_t ccnt;

    const int sh = t & 15;               // distinct copy per lane within group
    const int l = t & 63;                // lane
    const int w = t >> 6;                // wave
    if (t == 0) ccnt = 0u;
#pragma unroll
    for (int q = 0; q < 16; ++q) hist[q][t] = 0u;

    // block-min of d2 (floats all >= 0, no NaN -> float min == bits min)
    float mn = d[0];
#pragma unroll
    for (int s = 1; s < 32; ++s) mn = fminf(mn, d[s]);
#pragma unroll
    for (int off = 32; off >= 1; off >>= 1)
        mn = fminf(mn, __shfl_xor(mn, off, 64));
    if (l == 0) wmin[w] = mn;
    __syncthreads();                     // publishes wmin, hist zero, ccnt
    const uint32_t Mb = __float_as_uint(
        fminf(fminf(wmin[0], wmin[1]), fminf(wmin[2], wmin[3])));
    const uint32_t base = Mb >> 20;

    // windowed histogram level
#pragma unroll
    for (int s = 0; s < 32; ++s) {
        uint32_t hb = __float_as_uint(d[s]);
        if (hb < BIGBITS) {
            uint32_t bs = (hb >> 20) - base;
            bs = bs < 255u ? bs : 255u;
            atomicAdd(&hist[sh][bs], 1u);
        }
    }
    __syncthreads();
    uint32_t colsum = 0;
#pragma unroll
    for (int q = 0; q < 16; ++q) { colsum += hist[q][t]; hist[q][t] = 0u; }
    colrow[t] = colsum;
    __syncthreads();
    // all-wave redundant scan (each wave computes identical result)
    uint32_t bktW = 0u, rW = 0u, cBW = 0u;
    {
        uint32_t c0 = colrow[4 * l + 0], c1 = colrow[4 * l + 1];
        uint32_t c2 = colrow[4 * l + 2], c3 = colrow[4 * l + 3];
        uint32_t lsum = c0 + c1 + c2 + c3;
        uint32_t inc = lsum;
#pragma unroll
        for (int off = 1; off < 64; off <<= 1) {
            uint32_t o = __shfl_up(inc, off, 64);
            if (l >= off) inc += o;
        }
        uint32_t exc = inc - lsum;
        const uint32_t r = (uint32_t)KNB;
        bool hit = (exc < r && r <= inc);
        unsigned long long mb = __ballot(hit);
        uint32_t bkt = 0u, rnew = 0u, cBn = 0u;
        if (hit) {
            uint32_t e = exc;
            if (r <= e + c0)                { bkt = 4u * l + 0u; cBn = c0; }
            else if (r <= e + c0 + c1)      { bkt = 4u * l + 1u; cBn = c1; e += c0; }
            else if (r <= e + c0 + c1 + c2) { bkt = 4u * l + 2u; cBn = c2; e += c0 + c1; }
            else                            { bkt = 4u * l + 3u; cBn = c3; e += c0 + c1 + c2; }
            rnew = r - e;
        }
        const int src = (int)(__ffsll((long long)mb) - 1);
        bktW = __shfl(bkt, src, 64);
        rW = __shfl(rnew, src, 64);
        cBW = __shfl(cBn, src, 64);
    }

    uint32_t V;
    if (bktW < 255u && (uint32_t)KNB - rW + cBW <= 64u) {
        // fast path: exact conservative threshold from the window bucket
        V = ((base + bktW + 1u) << 20) - 1u;   // < 0x7F800000 always
    } else {
        // slow fallback: VERBATIM R14 4-level radix-select (hist already zero)
        __syncthreads();
        uint32_t pref = 0u, r = (uint32_t)KNB, cB = 0u;
        int exitShift = 0;
        for (int L = 0; L < 4; ++L) {
            const int shift = 24 - 8 * L;
            const uint32_t pmask = (L == 0) ? 0u : (0xFFFFFFFFu << (32 - 8 * L));
#pragma unroll
            for (int s = 0; s < 32; ++s) {
                uint32_t hb = __float_as_uint(d[s]);
                if ((hb & pmask) == pref && hb < BIGBITS)
                    atomicAdd(&hist[sh][(hb >> shift) & 255], 1u);
            }
            __syncthreads();
            uint32_t cs = 0;
#pragma unroll
            for (int q = 0; q < 16; ++q) { cs += hist[q][t]; hist[q][t] = 0u; }
            colrow[t] = cs;
            __syncthreads();
            uint32_t c0 = colrow[4 * l + 0], c1 = colrow[4 * l + 1];
            uint32_t c2 = colrow[4 * l + 2], c3 = colrow[4 * l + 3];
            uint32_t lsum = c0 + c1 + c2 + c3;
            uint32_t inc = lsum;
#pragma unroll
            for (int off = 1; off < 64; off <<= 1) {
                uint32_t o = __shfl_up(inc, off, 64);
                if (l >= off) inc += o;
            }
            uint32_t exc = inc - lsum;
            bool hit = (exc < r && r <= inc);
            unsigned long long mb = __ballot(hit);
            if (mb != 0ull) {
                uint32_t bkt = 0u, rnew = 0u, cBn = 0u;
                if (hit) {
                    uint32_t e = exc;
                    if (r <= e + c0)                { bkt = 4u * l + 0u; cBn = c0; }
                    else if (r <= e + c0 + c1)      { bkt = 4u * l + 1u; cBn = c1; e += c0; }
                    else if (r <= e + c0 + c1 + c2) { bkt = 4u * l + 2u; cBn = c2; e += c0 + c1; }
                    else                            { bkt = 4u * l + 3u; cBn = c3; e += c0 + c1 + c2; }
                    rnew = r - e;
                }
                const int src = (int)(__ffsll((long long)mb) - 1);
                bkt = __shfl(bkt, src, 64);
                rnew = __shfl(rnew, src, 64);
                cBn = __shfl(cBn, src, 64);
                pref = pref | (bkt << shift);
                r = rnew;
                cB = cBn;
            }
            if ((uint32_t)KNB - r + cB <= 64u) { exitShift = shift; break; }
        }
        V = pref | ((exitShift > 0) ? ((1u << exitShift) - 1u) : 0u);
    }

    // collect keys with d2bits <= V — wave-aggregated (1 atomic per wave-slice)
#pragma unroll
    for (int s = 0; s < 32; ++s) {
        uint32_t hb = __float_as_uint(d[s]);
        bool hit = (hb <= V);
        unsigned long long mask = __ballot(hit);
        if (mask != 0ull) {
            const int src = (int)(__ffsll((long long)mask) - 1);
            uint32_t basep = 0u;
            if (l == src) basep = atomicAdd(&ccnt, (uint32_t)__popcll(mask));
            basep = __shfl(basep, src, 64);
            if (hit) {
                uint32_t pos = basep +
                    (uint32_t)__popcll(mask & ((1ull << l) - 1ull));
                if (pos < 64u) cbuf[pos] = MKKEY(s);
            }
        }
    }
#undef MKKEY
    __syncthreads();
    const uint32_t n = ccnt < 64u ? ccnt : 64u;
    // wave 0: bitonic sort 64 via shfl (same network as proven sort_kernel)
    if (t < 64) {
        unsigned long long key = ((uint32_t)t < n) ? cbuf[t] : ~0ull;
#pragma unroll
        for (int k = 2; k <= 64; k <<= 1) {
            for (int j2 = k >> 1; j2 > 0; j2 >>= 1) {
                unsigned long long o = __shfl_xor(key, j2, 64);
                bool up = ((t & k) == 0);
                bool lower = ((t & j2) == 0);
                unsigned long long mn2 = key < o ? key : o;
                unsigned long long mx = key < o ? o : key;
                key = (up == lower) ? mn2 : mx;
            }
        }
        if (t < KNB) edgesT[(size_t)t * TOT + row] = (int)(key & 0xffffffffu);
    }
}

// ------ fused: threefry z-init + 5 Jacobi smooth steps + argsort, per batch --
// One block per batch, 1024 threads; z lives in LDS (bit-identical arithmetic:
// sequential k-sum, /(30+1e-5), invalid rows = 0, Jacobi gather-then-update).
__global__ __launch_bounds__(1024) void tail_kernel(const int* __restrict__ edgesT,
                                                    const int* __restrict__ C,
                                                    const float* __restrict__ prio,
                                                    int* __restrict__ out) {
    __shared__ float zc[NN];                 // 32 KiB
    __shared__ unsigned long long keys[NN];  // 64 KiB
    const int b = blockIdx.x;
    const int t = threadIdx.x;
    const int* Cb = C + (size_t)b * NN;

    // z init (partitionable threefry, counter = b*NN + n)
    for (int n = t; n < NN; n += 1024) {
        uint32_t o0, o1;
        threefry(0u, (uint32_t)(b * NN + n), o0, o1);
        uint32_t bits = o0 ^ o1;
        zc[n] = __uint_as_float((bits >> 9) | 0x3f800000u) - 1.0f;
    }
    __syncthreads();

    for (int step = 0; step < 5; ++step) {
        float acc[8];
#pragma unroll
        for (int q = 0; q < 8; ++q) {
            const int n = q * 1024 + t;
            float a = 0.0f;
            if (Cb[n] > 0) {
#pragma unroll
                for (int k = 0; k < KNB; ++k)
                    a = __fadd_rn(a, zc[edgesT[(size_t)k * TOT + b * NN + n]]);
                a = __fdiv_rn(a, __fadd_rn(30.0f, 1e-5f));
            }
            acc[q] = a;
        }
        __syncthreads();
#pragma unroll
        for (int q = 0; q < 8; ++q) zc[q * 1024 + t] = acc[q];
        __syncthreads();
    }

    // z += priority; stable ascending argsort (verbatim proven network)
    for (int i = t; i < NN; i += 1024) {
        float v = zc[i] + prio[(size_t)b * NN + i];
        uint32_t u = __float_as_uint(v);
        u ^= (u >> 31) ? 0xFFFFFFFFu : 0x80000000u;  // monotonic float->uint
        keys[i] = ((unsigned long long)u << 32) | (unsigned)i;
    }
    __syncthreads();
    for (int k = 2; k <= NN; k <<= 1) {
        for (int j = k >> 1; j > 0; j >>= 1) {
            for (int i = t; i < NN; i += 1024) {
                int ixj = i ^ j;
                if (ixj > i) {
                    unsigned long long a = keys[i], c = keys[ixj];
                    bool up = ((i & k) == 0);
                    if ((a > c) == up) { keys[i] = c; keys[ixj] = a; }
                }
            }
            __syncthreads();
        }
    }
    for (int i = t; i < NN; i += 1024)
        out[(size_t)b * NN + i] = (int)(keys[i] & 0xffffffffu);
}

extern "C" void kernel_launch(void* const* d_in, const int* in_sizes, int n_in,
                              void* d_out, int out_size, void* d_ws, size_t ws_size,
                              hipStream_t stream) {
    const float* X = (const float*)d_in[0];    // [4,8192,3] f32
    const int* C = (const int*)d_in[1];        // [4,8192] int32
    const float* prio = (const float*)d_in[2]; // [4,8192] f32
    int* out = (int*)d_out;                    // [4,8192] i32

    int* edgesT = (int*)d_ws;                  // [KNB][TOT]
    float* Xs = (float*)(edgesT + (size_t)TOT * KNB);  // [NB][3][NN]

    prep_kernel<<<TOT / 256, 256, 0, stream>>>(X, C, Xs);
    knn_kernel<<<TOT, 256, 0, stream>>>(Xs, X, edgesT);
    tail_kernel<<<NB, 1024, 0, stream>>>(edgesT, C, prio, out);
}

// Round 17
// 394.630 us; speedup vs baseline: 2.0544x; 2.0544x over previous
//
#include <hip/hip_runtime.h>
#include <stdint.h>

#define NB 4
#define NN 8192
#define KNB 30
#define TOT (NB * NN)

// ---------------- threefry2x32 (JAX-exact, key = [0, 42]) ----------------
__device__ __forceinline__ uint32_t rotl32(uint32_t v, int r) {
    return (v << r) | (v >> (32 - r));
}

__device__ __forceinline__ void threefry(uint32_t x0, uint32_t x1,
                                         uint32_t& o0, uint32_t& o1) {
    const uint32_t ks0 = 0u, ks1 = 42u, ks2 = 0u ^ 42u ^ 0x1BD11BDAu;
    x0 += ks0; x1 += ks1;
#define RND(r) { x0 += x1; x1 = rotl32(x1, r); x1 ^= x0; }
    RND(13) RND(15) RND(26) RND(6)
    x0 += ks1; x1 += ks2 + 1u;
    RND(17) RND(29) RND(16) RND(24)
    x0 += ks2; x1 += ks0 + 2u;
    RND(13) RND(15) RND(26) RND(6)
    x0 += ks0; x1 += ks1 + 3u;
    RND(17) RND(29) RND(16) RND(24)
    x0 += ks1; x1 += ks2 + 4u;
    RND(13) RND(15) RND(26) RND(6)
    x0 += ks2; x1 += ks0 + 5u;
#undef RND
    o0 = x0; o1 = x1;
}

// ---- fused: z init (partitionable threefry) + SoA transpose w/ inf-baking ----
__global__ void prep_kernel(const float* __restrict__ X,
                            const int* __restrict__ C,
                            float* __restrict__ z,
                            float* __restrict__ Xs) {
    int t = blockIdx.x * blockDim.x + threadIdx.x;
    if (t >= TOT) return;
    uint32_t o0, o1;
    threefry(0u, (uint32_t)t, o0, o1);
    uint32_t bits = o0 ^ o1;
    z[t] = __uint_as_float((bits >> 9) | 0x3f800000u) - 1.0f;

    const int b = t >> 13, n = t & (NN - 1);
    const bool valid = C[t] > 0;
    const float INF = __uint_as_float(0x7F800000u);
    const float* src = X + (size_t)t * 3;
    float* dst = Xs + (size_t)b * 3 * NN;
    dst[0 * NN + n] = valid ? src[0] : INF;
    dst[1 * NN + n] = valid ? src[1] : INF;
    dst[2 * NN + n] = valid ? src[2] : INF;
}

// ---------------- kNN: windowed single-level radix-select --------------------
// (R15-proven structure; collect = wave-aggregated ballot compact from R16)
__global__ __launch_bounds__(256) void knn_kernel(const float* __restrict__ Xs,
                                                  const float* __restrict__ X,
                                                  int* __restrict__ edgesT) {
    const int row = blockIdx.x;          // 0..TOT-1 (block per row)
    const int b = row >> 13;
    const int i = row & (NN - 1);
    const float* Xsb = Xs + (size_t)b * 3 * NN;
    const float xi = X[(size_t)b * NN * 3 + i * 3 + 0];
    const float yi = X[(size_t)b * NN * 3 + i * 3 + 1];
    const float zi = X[(size_t)b * NN * 3 + i * 3 + 2];
    const int t = threadIdx.x;
    const uint32_t BIGBITS = __float_as_uint(1e9f);

    float d[32];
#pragma unroll
    for (int g = 0; g < 8; ++g) {
        const int j0 = g * 1024 + t * 4;
        const float4 x4 = *(const float4*)(Xsb + 0 * NN + j0);
        const float4 y4 = *(const float4*)(Xsb + 1 * NN + j0);
        const float4 z4 = *(const float4*)(Xsb + 2 * NN + j0);
#define D2(q, xx, yy, zz)                                                      \
        {                                                                      \
            float dx = __fsub_rn(xi, (xx));                                    \
            float dy = __fsub_rn(yi, (yy));                                    \
            float dz = __fsub_rn(zi, (zz));                                    \
            float d2 = __fadd_rn(__fadd_rn(__fmul_rn(dx, dx),                  \
                                           __fmul_rn(dy, dy)),                 \
                                 __fmul_rn(dz, dz));                           \
            d2 = __fadd_rn(d2, ((j0 + (q)) == i) ? 1e9f : 0.0f);               \
            d[g * 4 + (q)] = d2;                                               \
        }
        D2(0, x4.x, y4.x, z4.x)
        D2(1, x4.y, y4.y, z4.y)
        D2(2, x4.z, y4.z, z4.z)
        D2(3, x4.w, y4.w, z4.w)
#undef D2
    }

#define MKKEY(s) ((((unsigned long long)__float_as_uint(d[(s)])) << 32) | \
                  (unsigned)((((s) >> 2) * 1024) + t * 4 + ((s) & 3)))

    __shared__ uint32_t hist[16][257];   // 16 copies; +1 pad: 257 % 32 == 1
    __shared__ uint32_t colrow[256];
    __shared__ float wmin[4];
    __shared__ unsigned long long cbuf[64];
    __shared__ uint32_t ccnt;

    const int sh = t & 15;               // distinct copy per lane within group
    const int l = t & 63;                // lane
    const int w = t >> 6;                // wave
    if (t == 0) ccnt = 0u;
#pragma unroll
    for (int q = 0; q < 16; ++q) hist[q][t] = 0u;

    // block-min of d2 (floats all >= 0, no NaN -> float min == bits min)
    float mn = d[0];
#pragma unroll
    for (int s = 1; s < 32; ++s) mn = fminf(mn, d[s]);
#pragma unroll
    for (int off = 32; off >= 1; off >>= 1)
        mn = fminf(mn, __shfl_xor(mn, off, 64));
    if (l == 0) wmin[w] = mn;
    __syncthreads();                     // publishes wmin, hist zero, ccnt
    const uint32_t Mb = __float_as_uint(
        fminf(fminf(wmin[0], wmin[1]), fminf(wmin[2], wmin[3])));
    const uint32_t base = Mb >> 20;

    // windowed histogram level
#pragma unroll
    for (int s = 0; s < 32; ++s) {
        uint32_t hb = __float_as_uint(d[s]);
        if (hb < BIGBITS) {
            uint32_t bs = (hb >> 20) - base;
            bs = bs < 255u ? bs : 255u;
            atomicAdd(&hist[sh][bs], 1u);
        }
    }
    __syncthreads();
    uint32_t colsum = 0;
#pragma unroll
    for (int q = 0; q < 16; ++q) { colsum += hist[q][t]; hist[q][t] = 0u; }
    colrow[t] = colsum;
    __syncthreads();
    // all-wave redundant scan (each wave computes identical result)
    uint32_t bktW = 0u, rW = 0u, cBW = 0u;
    {
        uint32_t c0 = colrow[4 * l + 0], c1 = colrow[4 * l + 1];
        uint32_t c2 = colrow[4 * l + 2], c3 = colrow[4 * l + 3];
        uint32_t lsum = c0 + c1 + c2 + c3;
        uint32_t inc = lsum;
#pragma unroll
        for (int off = 1; off < 64; off <<= 1) {
            uint32_t o = __shfl_up(inc, off, 64);
            if (l >= off) inc += o;
        }
        uint32_t exc = inc - lsum;
        const uint32_t r = (uint32_t)KNB;
        bool hit = (exc < r && r <= inc);
        unsigned long long mb = __ballot(hit);
        uint32_t bkt = 0u, rnew = 0u, cBn = 0u;
        if (hit) {
            uint32_t e = exc;
            if (r <= e + c0)                { bkt = 4u * l + 0u; cBn = c0; }
            else if (r <= e + c0 + c1)      { bkt = 4u * l + 1u; cBn = c1; e += c0; }
            else if (r <= e + c0 + c1 + c2) { bkt = 4u * l + 2u; cBn = c2; e += c0 + c1; }
            else                            { bkt = 4u * l + 3u; cBn = c3; e += c0 + c1 + c2; }
            rnew = r - e;
        }
        const int src = (int)(__ffsll((long long)mb) - 1);
        bktW = __shfl(bkt, src, 64);
        rW = __shfl(rnew, src, 64);
        cBW = __shfl(cBn, src, 64);
    }

    uint32_t V;
    if (bktW < 255u && (uint32_t)KNB - rW + cBW <= 64u) {
        // fast path: exact conservative threshold from the window bucket
        V = ((base + bktW + 1u) << 20) - 1u;   // < 0x7F800000 always
    } else {
        // slow fallback: VERBATIM R14 4-level radix-select (hist already zero)
        __syncthreads();
        uint32_t pref = 0u, r = (uint32_t)KNB, cB = 0u;
        int exitShift = 0;
        for (int L = 0; L < 4; ++L) {
            const int shift = 24 - 8 * L;
            const uint32_t pmask = (L == 0) ? 0u : (0xFFFFFFFFu << (32 - 8 * L));
#pragma unroll
            for (int s = 0; s < 32; ++s) {
                uint32_t hb = __float_as_uint(d[s]);
                if ((hb & pmask) == pref && hb < BIGBITS)
                    atomicAdd(&hist[sh][(hb >> shift) & 255], 1u);
            }
            __syncthreads();
            uint32_t cs = 0;
#pragma unroll
            for (int q = 0; q < 16; ++q) { cs += hist[q][t]; hist[q][t] = 0u; }
            colrow[t] = cs;
            __syncthreads();
            uint32_t c0 = colrow[4 * l + 0], c1 = colrow[4 * l + 1];
            uint32_t c2 = colrow[4 * l + 2], c3 = colrow[4 * l + 3];
            uint32_t lsum = c0 + c1 + c2 + c3;
            uint32_t inc = lsum;
#pragma unroll
            for (int off = 1; off < 64; off <<= 1) {
                uint32_t o = __shfl_up(inc, off, 64);
                if (l >= off) inc += o;
            }
            uint32_t exc = inc - lsum;
            bool hit = (exc < r && r <= inc);
            unsigned long long mb = __ballot(hit);
            if (mb != 0ull) {
                uint32_t bkt = 0u, rnew = 0u, cBn = 0u;
                if (hit) {
                    uint32_t e = exc;
                    if (r <= e + c0)                { bkt = 4u * l + 0u; cBn = c0; }
                    else if (r <= e + c0 + c1)      { bkt = 4u * l + 1u; cBn = c1; e += c0; }
                    else if (r <= e + c0 + c1 + c2) { bkt = 4u * l + 2u; cBn = c2; e += c0 + c1; }
                    else                            { bkt = 4u * l + 3u; cBn = c3; e += c0 + c1 + c2; }
                    rnew = r - e;
                }
                const int src = (int)(__ffsll((long long)mb) - 1);
                bkt = __shfl(bkt, src, 64);
                rnew = __shfl(rnew, src, 64);
                cBn = __shfl(cBn, src, 64);
                pref = pref | (bkt << shift);
                r = rnew;
                cB = cBn;
            }
            if ((uint32_t)KNB - r + cB <= 64u) { exitShift = shift; break; }
        }
        V = pref | ((exitShift > 0) ? ((1u << exitShift) - 1u) : 0u);
    }

    // collect keys with d2bits <= V — wave-aggregated (1 atomic per wave-slice)
#pragma unroll
    for (int s = 0; s < 32; ++s) {
        uint32_t hb = __float_as_uint(d[s]);
        bool hit = (hb <= V);
        unsigned long long mask = __ballot(hit);
        if (mask != 0ull) {
            const int src = (int)(__ffsll((long long)mask) - 1);
            uint32_t basep = 0u;
            if (l == src) basep = atomicAdd(&ccnt, (uint32_t)__popcll(mask));
            basep = __shfl(basep, src, 64);
            if (hit) {
                uint32_t pos = basep +
                    (uint32_t)__popcll(mask & ((1ull << l) - 1ull));
                if (pos < 64u) cbuf[pos] = MKKEY(s);
            }
        }
    }
#undef MKKEY
    __syncthreads();
    const uint32_t n = ccnt < 64u ? ccnt : 64u;
    // wave 0: bitonic sort 64 via shfl (same network as proven sort_kernel)
    if (t < 64) {
        unsigned long long key = ((uint32_t)t < n) ? cbuf[t] : ~0ull;
#pragma unroll
        for (int k = 2; k <= 64; k <<= 1) {
            for (int j2 = k >> 1; j2 > 0; j2 >>= 1) {
                unsigned long long o = __shfl_xor(key, j2, 64);
                bool up = ((t & k) == 0);
                bool lower = ((t & j2) == 0);
                unsigned long long mn2 = key < o ? key : o;
                unsigned long long mx = key < o ? o : key;
                key = (up == lower) ? mn2 : mx;
            }
        }
        if (t < KNB) edgesT[(size_t)t * TOT + row] = (int)(key & 0xffffffffu);
    }
}

// ------- one smoothing step (edgesT[k][row]: coalesced neighbor loads) -------
__global__ void smooth_kernel(const float* __restrict__ zin,
                              float* __restrict__ zout,
                              const int* __restrict__ edgesT,
                              const int* __restrict__ C) {
    int t = blockIdx.x * blockDim.x + threadIdx.x;
    if (t >= TOT) return;
    float acc = 0.0f;
    if (C[t] > 0) {
        const int b = t >> 13;
        const float* zb = zin + (size_t)b * NN;
#pragma unroll
        for (int k = 0; k < KNB; ++k)
            acc = __fadd_rn(acc, zb[edgesT[(size_t)k * TOT + t]]);
        acc = __fdiv_rn(acc, __fadd_rn(30.0f, 1e-5f));
    }
    zout[t] = acc;
}

// ---------------- z += priority; stable ascending argsort per batch ----------
__global__ __launch_bounds__(1024) void sort_kernel(const float* __restrict__ z,
                                                    const float* __restrict__ prio,
                                                    int* __restrict__ out) {
    __shared__ unsigned long long keys[NN];  // 64 KiB
    const int b = blockIdx.x;
    for (int i = threadIdx.x; i < NN; i += 1024) {
        float v = z[(size_t)b * NN + i] + prio[(size_t)b * NN + i];
        uint32_t u = __float_as_uint(v);
        u ^= (u >> 31) ? 0xFFFFFFFFu : 0x80000000u;  // monotonic float->uint
        keys[i] = ((unsigned long long)u << 32) | (unsigned)i;
    }
    __syncthreads();
    for (int k = 2; k <= NN; k <<= 1) {
        for (int j = k >> 1; j > 0; j >>= 1) {
            for (int i = threadIdx.x; i < NN; i += 1024) {
                int ixj = i ^ j;
                if (ixj > i) {
                    unsigned long long a = keys[i], c = keys[ixj];
                    bool up = ((i & k) == 0);
                    if ((a > c) == up) { keys[i] = c; keys[ixj] = a; }
                }
            }
            __syncthreads();
        }
    }
    for (int i = threadIdx.x; i < NN; i += 1024)
        out[(size_t)b * NN + i] = (int)(keys[i] & 0xffffffffu);
}

extern "C" void kernel_launch(void* const* d_in, const int* in_sizes, int n_in,
                              void* d_out, int out_size, void* d_ws, size_t ws_size,
                              hipStream_t stream) {
    const float* X = (const float*)d_in[0];    // [4,8192,3] f32
    const int* C = (const int*)d_in[1];        // [4,8192] int32
    const float* prio = (const float*)d_in[2]; // [4,8192] f32
    int* out = (int*)d_out;                    // [4,8192] i32

    float* z0 = (float*)d_ws;
    float* z1 = z0 + TOT;
    int* edgesT = (int*)(z1 + TOT);            // [KNB][TOT]
    float* Xs = (float*)(edgesT + (size_t)TOT * KNB);  // [NB][3][NN]

    prep_kernel<<<TOT / 256, 256, 0, stream>>>(X, C, z0, Xs);
    knn_kernel<<<TOT, 256, 0, stream>>>(Xs, X, edgesT);

    float* cur = z0;
    float* nxt = z1;
    for (int s = 0; s < 5; ++s) {
        smooth_kernel<<<TOT / 256, 256, 0, stream>>>(cur, nxt, edgesT, C);
        float* tmp = cur; cur = nxt; nxt = tmp;
    }
    sort_kernel<<<NB, 1024, 0, stream>>>(cur, prio, out);
}

// Round 18
// 340.821 us; speedup vs baseline: 2.3788x; 1.1579x over previous
//
#include <hip/hip_runtime.h>
#include <stdint.h>

#define NB 4
#define NN 8192
#define KNB 30
#define TOT (NB * NN)

// ---------------- threefry2x32 (JAX-exact, key = [0, 42]) ----------------
__device__ __forceinline__ uint32_t rotl32(uint32_t v, int r) {
    return (v << r) | (v >> (32 - r));
}

__device__ __forceinline__ void threefry(uint32_t x0, uint32_t x1,
                                         uint32_t& o0, uint32_t& o1) {
    const uint32_t ks0 = 0u, ks1 = 42u, ks2 = 0u ^ 42u ^ 0x1BD11BDAu;
    x0 += ks0; x1 += ks1;
#define RND(r) { x0 += x1; x1 = rotl32(x1, r); x1 ^= x0; }
    RND(13) RND(15) RND(26) RND(6)
    x0 += ks1; x1 += ks2 + 1u;
    RND(17) RND(29) RND(16) RND(24)
    x0 += ks2; x1 += ks0 + 2u;
    RND(13) RND(15) RND(26) RND(6)
    x0 += ks0; x1 += ks1 + 3u;
    RND(17) RND(29) RND(16) RND(24)
    x0 += ks1; x1 += ks2 + 4u;
    RND(13) RND(15) RND(26) RND(6)
    x0 += ks2; x1 += ks0 + 5u;
#undef RND
    o0 = x0; o1 = x1;
}

// ---- fused: z init (partitionable threefry) + SoA transpose w/ inf-baking ----
__global__ void prep_kernel(const float* __restrict__ X,
                            const int* __restrict__ C,
                            float* __restrict__ z,
                            float* __restrict__ Xs) {
    int t = blockIdx.x * blockDim.x + threadIdx.x;
    if (t >= TOT) return;
    uint32_t o0, o1;
    threefry(0u, (uint32_t)t, o0, o1);
    uint32_t bits = o0 ^ o1;
    z[t] = __uint_as_float((bits >> 9) | 0x3f800000u) - 1.0f;

    const int b = t >> 13, n = t & (NN - 1);
    const bool valid = C[t] > 0;
    const float INF = __uint_as_float(0x7F800000u);
    const float* src = X + (size_t)t * 3;
    float* dst = Xs + (size_t)b * 3 * NN;
    dst[0 * NN + n] = valid ? src[0] : INF;
    dst[1 * NN + n] = valid ? src[1] : INF;
    dst[2 * NN + n] = valid ? src[2] : INF;
}

// ---------------- kNN: dual-row windowed radix-select ------------------------
// One block serves rows 2k, 2k+1 (same batch: NN even). Candidates loaded once;
// per-row ladder/select/collect VERBATIM R15 (proven). Fallback = R15 4-level.
__global__ __launch_bounds__(256) void knn_kernel(const float* __restrict__ Xs,
                                                  const float* __restrict__ X,
                                                  int* __restrict__ edgesT) {
    const int rowA = blockIdx.x * 2;
    const int rowB = rowA + 1;
    const int b = rowA >> 13;
    const int iA = rowA & (NN - 1);
    const int iB = iA + 1;
    const float* Xsb = Xs + (size_t)b * 3 * NN;
    const float* Xq = X + (size_t)b * NN * 3;
    const float xiA = Xq[iA * 3 + 0], yiA = Xq[iA * 3 + 1], ziA = Xq[iA * 3 + 2];
    const float xiB = Xq[iB * 3 + 0], yiB = Xq[iB * 3 + 1], ziB = Xq[iB * 3 + 2];
    const int t = threadIdx.x;
    const uint32_t BIGBITS = __float_as_uint(1e9f);

    float dA[32], dB[32];
#pragma unroll
    for (int g = 0; g < 8; ++g) {
        const int j0 = g * 1024 + t * 4;
        const float4 x4 = *(const float4*)(Xsb + 0 * NN + j0);
        const float4 y4 = *(const float4*)(Xsb + 1 * NN + j0);
        const float4 z4 = *(const float4*)(Xsb + 2 * NN + j0);
#define D2(q, xx, yy, zz)                                                      \
        {                                                                      \
            float dx = __fsub_rn(xiA, (xx));                                   \
            float dy = __fsub_rn(yiA, (yy));                                   \
            float dz = __fsub_rn(ziA, (zz));                                   \
            float d2 = __fadd_rn(__fadd_rn(__fmul_rn(dx, dx),                  \
                                           __fmul_rn(dy, dy)),                 \
                                 __fmul_rn(dz, dz));                           \
            dA[g * 4 + (q)] = __fadd_rn(d2, ((j0 + (q)) == iA) ? 1e9f : 0.0f); \
            float ex = __fsub_rn(xiB, (xx));                                   \
            float ey = __fsub_rn(yiB, (yy));                                   \
            float ez = __fsub_rn(ziB, (zz));                                   \
            float e2 = __fadd_rn(__fadd_rn(__fmul_rn(ex, ex),                  \
                                           __fmul_rn(ey, ey)),                 \
                                 __fmul_rn(ez, ez));                           \
            dB[g * 4 + (q)] = __fadd_rn(e2, ((j0 + (q)) == iB) ? 1e9f : 0.0f); \
        }
        D2(0, x4.x, y4.x, z4.x)
        D2(1, x4.y, y4.y, z4.y)
        D2(2, x4.z, y4.z, z4.z)
        D2(3, x4.w, y4.w, z4.w)
#undef D2
    }

#define MKKEY(D, s) ((((unsigned long long)__float_as_uint(D[(s)])) << 32) | \
                     (unsigned)((((s) >> 2) * 1024) + t * 4 + ((s) & 3)))

    __shared__ uint32_t histA[16][257];  // +1 pad: 257 % 32 == 1
    __shared__ uint32_t histB[16][257];
    __shared__ uint32_t colrowA[256], colrowB[256];
    __shared__ float wminA[4], wminB[4];
    __shared__ unsigned long long cbufA[64], cbufB[64];
    __shared__ uint32_t ccntA, ccntB;

    const int sh = t & 15;               // distinct copy per lane within group
    const int l = t & 63;                // lane
    const int w = t >> 6;                // wave
    if (t == 0) { ccntA = 0u; ccntB = 0u; }
#pragma unroll
    for (int q = 0; q < 16; ++q) { histA[q][t] = 0u; histB[q][t] = 0u; }

    // block-min of d2 per row (floats >= 0, no NaN -> float min == bits min)
    float mnA = dA[0], mnB = dB[0];
#pragma unroll
    for (int s = 1; s < 32; ++s) { mnA = fminf(mnA, dA[s]); mnB = fminf(mnB, dB[s]); }
#pragma unroll
    for (int off = 32; off >= 1; off >>= 1) {
        mnA = fminf(mnA, __shfl_xor(mnA, off, 64));
        mnB = fminf(mnB, __shfl_xor(mnB, off, 64));
    }
    if (l == 0) { wminA[w] = mnA; wminB[w] = mnB; }
    __syncthreads();                     // publishes wmin, hist zero, ccnt
    const uint32_t baseA = __float_as_uint(
        fminf(fminf(wminA[0], wminA[1]), fminf(wminA[2], wminA[3]))) >> 20;
    const uint32_t baseB = __float_as_uint(
        fminf(fminf(wminB[0], wminB[1]), fminf(wminB[2], wminB[3]))) >> 20;

    // windowed histogram level, both rows in one pass
#pragma unroll
    for (int s = 0; s < 32; ++s) {
        uint32_t hbA = __float_as_uint(dA[s]);
        if (hbA < BIGBITS) {
            uint32_t bs = (hbA >> 20) - baseA;
            bs = bs < 255u ? bs : 255u;
            atomicAdd(&histA[sh][bs], 1u);
        }
        uint32_t hbB = __float_as_uint(dB[s]);
        if (hbB < BIGBITS) {
            uint32_t bs = (hbB >> 20) - baseB;
            bs = bs < 255u ? bs : 255u;
            atomicAdd(&histB[sh][bs], 1u);
        }
    }
    __syncthreads();
    {
        uint32_t csA = 0, csB = 0;
#pragma unroll
        for (int q = 0; q < 16; ++q) {
            csA += histA[q][t]; histA[q][t] = 0u;
            csB += histB[q][t]; histB[q][t] = 0u;
        }
        colrowA[t] = csA;
        colrowB[t] = csB;
    }
    __syncthreads();

    // all-wave redundant scan per row (registers; identical across waves)
#define SCAN(COLROW, BKT, RR, CB)                                              \
    {                                                                          \
        uint32_t c0 = COLROW[4 * l + 0], c1 = COLROW[4 * l + 1];               \
        uint32_t c2 = COLROW[4 * l + 2], c3 = COLROW[4 * l + 3];               \
        uint32_t lsum = c0 + c1 + c2 + c3;                                     \
        uint32_t inc = lsum;                                                   \
        _Pragma("unroll")                                                      \
        for (int off = 1; off < 64; off <<= 1) {                               \
            uint32_t o = __shfl_up(inc, off, 64);                              \
            if (l >= off) inc += o;                                            \
        }                                                                      \
        uint32_t exc = inc - lsum;                                             \
        const uint32_t r0 = (uint32_t)KNB;                                     \
        bool hit = (exc < r0 && r0 <= inc);                                    \
        unsigned long long mb = __ballot(hit);                                 \
        uint32_t bkt = 0u, rnew = 0u, cBn = 0u;                                \
        if (hit) {                                                             \
            uint32_t e = exc;                                                  \
            if (r0 <= e + c0)                { bkt = 4u*l+0u; cBn = c0; }      \
            else if (r0 <= e + c0 + c1)      { bkt = 4u*l+1u; cBn = c1; e += c0; } \
            else if (r0 <= e + c0 + c1 + c2) { bkt = 4u*l+2u; cBn = c2; e += c0 + c1; } \
            else                             { bkt = 4u*l+3u; cBn = c3; e += c0 + c1 + c2; } \
            rnew = r0 - e;                                                     \
        }                                                                      \
        const int srcl = (int)(__ffsll((long long)mb) - 1);                    \
        BKT = __shfl(bkt, srcl, 64);                                           \
        RR = __shfl(rnew, srcl, 64);                                           \
        CB = __shfl(cBn, srcl, 64);                                            \
    }

    uint32_t bktA, rA, cBA, bktB, rB, cBB;
    SCAN(colrowA, bktA, rA, cBA)
    SCAN(colrowB, bktB, rB, cBB)

    // slow fallback (rare; block-uniform per row): VERBATIM R14/R15 4-level
#define FALLBACK(D, HIST, COLROW, VOUT)                                        \
    {                                                                          \
        uint32_t pref = 0u, r = (uint32_t)KNB, cB = 0u;                        \
        int exitShift = 0;                                                     \
        for (int L = 0; L < 4; ++L) {                                          \
            const int shift = 24 - 8 * L;                                      \
            const uint32_t pmask = (L == 0) ? 0u : (0xFFFFFFFFu << (32 - 8 * L)); \
            _Pragma("unroll")                                                  \
            for (int s = 0; s < 32; ++s) {                                     \
                uint32_t hb = __float_as_uint(D[s]);                           \
                if ((hb & pmask) == pref && hb < BIGBITS)                      \
                    atomicAdd(&HIST[sh][(hb >> shift) & 255], 1u);             \
            }                                                                  \
            __syncthreads();                                                   \
            uint32_t cs = 0;                                                   \
            _Pragma("unroll")                                                  \
            for (int q = 0; q < 16; ++q) { cs += HIST[q][t]; HIST[q][t] = 0u; } \
            COLROW[t] = cs;                                                    \
            __syncthreads();                                                   \
            uint32_t bkt2, rnew2, cb2;                                         \
            SCAN(COLROW, bkt2, rnew2, cb2)                                     \
            unsigned long long any = __ballot(rnew2 != 0u || cb2 != 0u);       \
            if (any != 0ull) {                                                 \
                pref = pref | (bkt2 << shift);                                 \
                r = rnew2;                                                     \
                cB = cb2;                                                      \
            }                                                                  \
            if ((uint32_t)KNB - r + cB <= 64u) { exitShift = shift; break; }   \
        }                                                                      \
        VOUT = pref | ((exitShift > 0) ? ((1u << exitShift) - 1u) : 0u);       \
    }

    uint32_t V_A, V_B;
    if (bktA < 255u && (uint32_t)KNB - rA + cBA <= 64u) {
        V_A = ((baseA + bktA + 1u) << 20) - 1u;
    } else {
        __syncthreads();
        FALLBACK(dA, histA, colrowA, V_A)
    }
    if (bktB < 255u && (uint32_t)KNB - rB + cBB <= 64u) {
        V_B = ((baseB + bktB + 1u) << 20) - 1u;
    } else {
        __syncthreads();
        FALLBACK(dB, histB, colrowB, V_B)
    }
#undef FALLBACK
#undef SCAN

    // collect (simple per-hit atomic — R15-proven faster than ballot compact)
#pragma unroll
    for (int s = 0; s < 32; ++s) {
        uint32_t hbA = __float_as_uint(dA[s]);
        if (hbA <= V_A) {
            uint32_t p = atomicAdd(&ccntA, 1u);
            if (p < 64u) cbufA[p] = MKKEY(dA, s);
        }
        uint32_t hbB = __float_as_uint(dB[s]);
        if (hbB <= V_B) {
            uint32_t p = atomicAdd(&ccntB, 1u);
            if (p < 64u) cbufB[p] = MKKEY(dB, s);
        }
    }
#undef MKKEY
    __syncthreads();
    // wave 0 sorts row A, wave 1 sorts row B (proven bitonic-64 network)
    if (w < 2) {
        const uint32_t n = (w == 0) ? (ccntA < 64u ? ccntA : 64u)
                                    : (ccntB < 64u ? ccntB : 64u);
        unsigned long long key =
            ((uint32_t)l < n) ? (w == 0 ? cbufA[l] : cbufB[l]) : ~0ull;
#pragma unroll
        for (int k = 2; k <= 64; k <<= 1) {
            for (int j2 = k >> 1; j2 > 0; j2 >>= 1) {
                unsigned long long o = __shfl_xor(key, j2, 64);
                bool up = ((l & k) == 0);
                bool lower = ((l & j2) == 0);
                unsigned long long mn2 = key < o ? key : o;
                unsigned long long mx = key < o ? o : key;
                key = (up == lower) ? mn2 : mx;
            }
        }
        if (l < KNB)
            edgesT[(size_t)l * TOT + (w == 0 ? rowA : rowB)] =
                (int)(key & 0xffffffffu);
    }
}

// ------- one smoothing step (edgesT[k][row]: coalesced neighbor loads) -------
__global__ void smooth_kernel(const float* __restrict__ zin,
                              float* __restrict__ zout,
                              const int* __restrict__ edgesT,
                              const int* __restrict__ C) {
    int t = blockIdx.x * blockDim.x + threadIdx.x;
    if (t >= TOT) return;
    float acc = 0.0f;
    if (C[t] > 0) {
        const int b = t >> 13;
        const float* zb = zin + (size_t)b * NN;
#pragma unroll
        for (int k = 0; k < KNB; ++k)
            acc = __fadd_rn(acc, zb[edgesT[(size_t)k * TOT + t]]);
        acc = __fdiv_rn(acc, __fadd_rn(30.0f, 1e-5f));
    }
    zout[t] = acc;
}

// ---------------- z += priority; stable ascending argsort per batch ----------
__global__ __launch_bounds__(1024) void sort_kernel(const float* __restrict__ z,
                                                    const float* __restrict__ prio,
                                                    int* __restrict__ out) {
    __shared__ unsigned long long keys[NN];  // 64 KiB
    const int b = blockIdx.x;
    for (int i = threadIdx.x; i < NN; i += 1024) {
        float v = z[(size_t)b * NN + i] + prio[(size_t)b * NN + i];
        uint32_t u = __float_as_uint(v);
        u ^= (u >> 31) ? 0xFFFFFFFFu : 0x80000000u;  // monotonic float->uint
        keys[i] = ((unsigned long long)u << 32) | (unsigned)i;
    }
    __syncthreads();
    for (int k = 2; k <= NN; k <<= 1) {
        for (int j = k >> 1; j > 0; j >>= 1) {
            for (int i = threadIdx.x; i < NN; i += 1024) {
                int ixj = i ^ j;
                if (ixj > i) {
                    unsigned long long a = keys[i], c = keys[ixj];
                    bool up = ((i & k) == 0);
                    if ((a > c) == up) { keys[i] = c; keys[ixj] = a; }
                }
            }
            __syncthreads();
        }
    }
    for (int i = threadIdx.x; i < NN; i += 1024)
        out[(size_t)b * NN + i] = (int)(keys[i] & 0xffffffffu);
}

extern "C" void kernel_launch(void* const* d_in, const int* in_sizes, int n_in,
                              void* d_out, int out_size, void* d_ws, size_t ws_size,
                              hipStream_t stream) {
    const float* X = (const float*)d_in[0];    // [4,8192,3] f32
    const int* C = (const int*)d_in[1];        // [4,8192] int32
    const float* prio = (const float*)d_in[2]; // [4,8192] f32
    int* out = (int*)d_out;                    // [4,8192] i32

    float* z0 = (float*)d_ws;
    float* z1 = z0 + TOT;
    int* edgesT = (int*)(z1 + TOT);            // [KNB][TOT]
    float* Xs = (float*)(edgesT + (size_t)TOT * KNB);  // [NB][3][NN]

    prep_kernel<<<TOT / 256, 256, 0, stream>>>(X, C, z0, Xs);
    knn_kernel<<<TOT / 2, 256, 0, stream>>>(Xs, X, edgesT);

    float* cur = z0;
    float* nxt = z1;
    for (int s = 0; s < 5; ++s) {
        smooth_kernel<<<TOT / 256, 256, 0, stream>>>(cur, nxt, edgesT, C);
        float* tmp = cur; cur = nxt; nxt = tmp;
    }
    sort_kernel<<<NB, 1024, 0, stream>>>(cur, prio, out);
}

// Round 19
// 328.715 us; speedup vs baseline: 2.4664x; 1.0368x over previous
//
#include <hip/hip_runtime.h>
#include <stdint.h>

#define NB 4
#define NN 8192
#define KNB 30
#define TOT (NB * NN)

// ---------------- threefry2x32 (JAX-exact, key = [0, 42]) ----------------
__device__ __forceinline__ uint32_t rotl32(uint32_t v, int r) {
    return (v << r) | (v >> (32 - r));
}

__device__ __forceinline__ void threefry(uint32_t x0, uint32_t x1,
                                         uint32_t& o0, uint32_t& o1) {
    const uint32_t ks0 = 0u, ks1 = 42u, ks2 = 0u ^ 42u ^ 0x1BD11BDAu;
    x0 += ks0; x1 += ks1;
#define RND(r) { x0 += x1; x1 = rotl32(x1, r); x1 ^= x0; }
    RND(13) RND(15) RND(26) RND(6)
    x0 += ks1; x1 += ks2 + 1u;
    RND(17) RND(29) RND(16) RND(24)
    x0 += ks2; x1 += ks0 + 2u;
    RND(13) RND(15) RND(26) RND(6)
    x0 += ks0; x1 += ks1 + 3u;
    RND(17) RND(29) RND(16) RND(24)
    x0 += ks1; x1 += ks2 + 4u;
    RND(13) RND(15) RND(26) RND(6)
    x0 += ks2; x1 += ks0 + 5u;
#undef RND
    o0 = x0; o1 = x1;
}

// ---- fused: z init (partitionable threefry) + SoA transpose w/ inf-baking ----
__global__ void prep_kernel(const float* __restrict__ X,
                            const int* __restrict__ C,
                            float* __restrict__ z,
                            float* __restrict__ Xs) {
    int t = blockIdx.x * blockDim.x + threadIdx.x;
    if (t >= TOT) return;
    uint32_t o0, o1;
    threefry(0u, (uint32_t)t, o0, o1);
    uint32_t bits = o0 ^ o1;
    z[t] = __uint_as_float((bits >> 9) | 0x3f800000u) - 1.0f;

    const int b = t >> 13, n = t & (NN - 1);
    const bool valid = C[t] > 0;
    const float INF = __uint_as_float(0x7F800000u);
    const float* src = X + (size_t)t * 3;
    float* dst = Xs + (size_t)b * 3 * NN;
    dst[0 * NN + n] = valid ? src[0] : INF;
    dst[1 * NN + n] = valid ? src[1] : INF;
    dst[2 * NN + n] = valid ? src[2] : INF;
}

// ---------------- kNN: dual-row windowed radix-select, packed histogram ------
// One block serves rows 2k, 2k+1. PACKED hist: row A counts in low 16 bits,
// row B in high 16 (per-copy bucket count <= 512 -> no carry). 16 copies kept
// (4-way same-address degree). LDS ~19.6KB -> 8 blocks/CU (was 36KB/4).
// Lazy zero: fast path never re-zeroes; fallback zeroes for itself.
__global__ __launch_bounds__(256) void knn_kernel(const float* __restrict__ Xs,
                                                  const float* __restrict__ X,
                                                  int* __restrict__ edgesT) {
    const int rowA = blockIdx.x * 2;
    const int rowB = rowA + 1;
    const int b = rowA >> 13;
    const int iA = rowA & (NN - 1);
    const int iB = iA + 1;
    const float* Xsb = Xs + (size_t)b * 3 * NN;
    const float* Xq = X + (size_t)b * NN * 3;
    const float xiA = Xq[iA * 3 + 0], yiA = Xq[iA * 3 + 1], ziA = Xq[iA * 3 + 2];
    const float xiB = Xq[iB * 3 + 0], yiB = Xq[iB * 3 + 1], ziB = Xq[iB * 3 + 2];
    const int t = threadIdx.x;
    const uint32_t BIGBITS = __float_as_uint(1e9f);

    float dA[32], dB[32];
#pragma unroll
    for (int g = 0; g < 8; ++g) {
        const int j0 = g * 1024 + t * 4;
        const float4 x4 = *(const float4*)(Xsb + 0 * NN + j0);
        const float4 y4 = *(const float4*)(Xsb + 1 * NN + j0);
        const float4 z4 = *(const float4*)(Xsb + 2 * NN + j0);
#define D2(q, xx, yy, zz)                                                      \
        {                                                                      \
            float dx = __fsub_rn(xiA, (xx));                                   \
            float dy = __fsub_rn(yiA, (yy));                                   \
            float dz = __fsub_rn(ziA, (zz));                                   \
            float d2 = __fadd_rn(__fadd_rn(__fmul_rn(dx, dx),                  \
                                           __fmul_rn(dy, dy)),                 \
                                 __fmul_rn(dz, dz));                           \
            dA[g * 4 + (q)] = __fadd_rn(d2, ((j0 + (q)) == iA) ? 1e9f : 0.0f); \
            float ex = __fsub_rn(xiB, (xx));                                   \
            float ey = __fsub_rn(yiB, (yy));                                   \
            float ez = __fsub_rn(ziB, (zz));                                   \
            float e2 = __fadd_rn(__fadd_rn(__fmul_rn(ex, ex),                  \
                                           __fmul_rn(ey, ey)),                 \
                                 __fmul_rn(ez, ez));                           \
            dB[g * 4 + (q)] = __fadd_rn(e2, ((j0 + (q)) == iB) ? 1e9f : 0.0f); \
        }
        D2(0, x4.x, y4.x, z4.x)
        D2(1, x4.y, y4.y, z4.y)
        D2(2, x4.z, y4.z, z4.z)
        D2(3, x4.w, y4.w, z4.w)
#undef D2
    }

#define MKKEY(D, s) ((((unsigned long long)__float_as_uint(D[(s)])) << 32) | \
                     (unsigned)((((s) >> 2) * 1024) + t * 4 + ((s) & 3)))

    __shared__ uint32_t hist[16][257];   // packed A|B; +1 pad: 257 % 32 == 1
    __shared__ uint32_t colrowA[256], colrowB[256];
    __shared__ float wminA[4], wminB[4];
    __shared__ unsigned long long cbufA[64], cbufB[64];
    __shared__ uint32_t ccntA, ccntB;

    const int sh = t & 15;               // distinct copy per lane within group
    const int l = t & 63;                // lane
    const int w = t >> 6;                // wave
    if (t == 0) { ccntA = 0u; ccntB = 0u; }
#pragma unroll
    for (int q = 0; q < 16; ++q) hist[q][t] = 0u;

    // block-min of d2 per row (floats >= 0, no NaN -> float min == bits min)
    float mnA = dA[0], mnB = dB[0];
#pragma unroll
    for (int s = 1; s < 32; ++s) { mnA = fminf(mnA, dA[s]); mnB = fminf(mnB, dB[s]); }
#pragma unroll
    for (int off = 32; off >= 1; off >>= 1) {
        mnA = fminf(mnA, __shfl_xor(mnA, off, 64));
        mnB = fminf(mnB, __shfl_xor(mnB, off, 64));
    }
    if (l == 0) { wminA[w] = mnA; wminB[w] = mnB; }
    __syncthreads();                     // publishes wmin, hist zero, ccnt
    const uint32_t baseA = __float_as_uint(
        fminf(fminf(wminA[0], wminA[1]), fminf(wminA[2], wminA[3]))) >> 20;
    const uint32_t baseB = __float_as_uint(
        fminf(fminf(wminB[0], wminB[1]), fminf(wminB[2], wminB[3]))) >> 20;

    // windowed histogram level, both rows packed into one array
#pragma unroll
    for (int s = 0; s < 32; ++s) {
        uint32_t hbA = __float_as_uint(dA[s]);
        if (hbA < BIGBITS) {
            uint32_t bs = (hbA >> 20) - baseA;
            bs = bs < 255u ? bs : 255u;
            atomicAdd(&hist[sh][bs], 1u);
        }
        uint32_t hbB = __float_as_uint(dB[s]);
        if (hbB < BIGBITS) {
            uint32_t bs = (hbB >> 20) - baseB;
            bs = bs < 255u ? bs : 255u;
            atomicAdd(&hist[sh][bs], 0x10000u);
        }
    }
    __syncthreads();
    {
        uint32_t csA = 0, csB = 0;
#pragma unroll
        for (int q = 0; q < 16; ++q) {
            uint32_t h = hist[q][t];     // lazy: no re-zero on fast path
            csA += h & 0xFFFFu;
            csB += h >> 16;
        }
        colrowA[t] = csA;
        colrowB[t] = csB;
    }
    __syncthreads();

    // all-wave redundant scan per row (registers; identical across waves)
#define SCAN(COLROW, BKT, RR, CB)                                              \
    {                                                                          \
        uint32_t c0 = COLROW[4 * l + 0], c1 = COLROW[4 * l + 1];               \
        uint32_t c2 = COLROW[4 * l + 2], c3 = COLROW[4 * l + 3];               \
        uint32_t lsum = c0 + c1 + c2 + c3;                                     \
        uint32_t inc = lsum;                                                   \
        _Pragma("unroll")                                                      \
        for (int off = 1; off < 64; off <<= 1) {                               \
            uint32_t o = __shfl_up(inc, off, 64);                              \
            if (l >= off) inc += o;                                            \
        }                                                                      \
        uint32_t exc = inc - lsum;                                             \
        const uint32_t r0 = (uint32_t)KNB;                                     \
        bool hit = (exc < r0 && r0 <= inc);                                    \
        unsigned long long mb = __ballot(hit);                                 \
        uint32_t bkt = 0u, rnew = 0u, cBn = 0u;                                \
        if (hit) {                                                             \
            uint32_t e = exc;                                                  \
            if (r0 <= e + c0)                { bkt = 4u*l+0u; cBn = c0; }      \
            else if (r0 <= e + c0 + c1)      { bkt = 4u*l+1u; cBn = c1; e += c0; } \
            else if (r0 <= e + c0 + c1 + c2) { bkt = 4u*l+2u; cBn = c2; e += c0 + c1; } \
            else                             { bkt = 4u*l+3u; cBn = c3; e += c0 + c1 + c2; } \
            rnew = r0 - e;                                                     \
        }                                                                      \
        const int srcl = (int)(__ffsll((long long)mb) - 1);                    \
        BKT = __shfl(bkt, srcl, 64);                                           \
        RR = __shfl(rnew, srcl, 64);                                           \
        CB = __shfl(cBn, srcl, 64);                                            \
    }

    uint32_t bktA, rA, cBA, bktB, rB, cBB;
    SCAN(colrowA, bktA, rA, cBA)
    SCAN(colrowB, bktB, rB, cBB)

    // slow fallback (rare; block-uniform per row): R15 4-level, full-width
    // counts, zeroes hist for itself (lazy-zero scheme).
#define FALLBACK(D, COLROW, VOUT)                                              \
    {                                                                          \
        _Pragma("unroll")                                                      \
        for (int q = 0; q < 16; ++q) hist[q][t] = 0u;                          \
        __syncthreads();                                                       \
        uint32_t pref = 0u, r = (uint32_t)KNB, cB = 0u;                        \
        int exitShift = 0;                                                     \
        for (int L = 0; L < 4; ++L) {                                          \
            const int shift = 24 - 8 * L;                                      \
            const uint32_t pmask = (L == 0) ? 0u : (0xFFFFFFFFu << (32 - 8 * L)); \
            _Pragma("unroll")                                                  \
            for (int s = 0; s < 32; ++s) {                                     \
                uint32_t hb = __float_as_uint(D[s]);                           \
                if ((hb & pmask) == pref && hb < BIGBITS)                      \
                    atomicAdd(&hist[sh][(hb >> shift) & 255], 1u);             \
            }                                                                  \
            __syncthreads();                                                   \
            uint32_t cs = 0;                                                   \
            _Pragma("unroll")                                                  \
            for (int q = 0; q < 16; ++q) { cs += hist[q][t]; hist[q][t] = 0u; } \
            COLROW[t] = cs;                                                    \
            __syncthreads();                                                   \
            uint32_t bkt2, rnew2, cb2;                                         \
            SCAN(COLROW, bkt2, rnew2, cb2)                                     \
            unsigned long long any = __ballot(rnew2 != 0u || cb2 != 0u);       \
            if (any != 0ull) {                                                 \
                pref = pref | (bkt2 << shift);                                 \
                r = rnew2;                                                     \
                cB = cb2;                                                      \
            }                                                                  \
            if ((uint32_t)KNB - r + cB <= 64u) { exitShift = shift; break; }   \
        }                                                                      \
        VOUT = pref | ((exitShift > 0) ? ((1u << exitShift) - 1u) : 0u);       \
    }

    uint32_t V_A, V_B;
    if (bktA < 255u && (uint32_t)KNB - rA + cBA <= 64u) {
        V_A = ((baseA + bktA + 1u) << 20) - 1u;
    } else {
        __syncthreads();
        FALLBACK(dA, colrowA, V_A)
    }
    if (bktB < 255u && (uint32_t)KNB - rB + cBB <= 64u) {
        V_B = ((baseB + bktB + 1u) << 20) - 1u;
    } else {
        __syncthreads();
        FALLBACK(dB, colrowB, V_B)
    }
#undef FALLBACK
#undef SCAN

    // collect (simple per-hit atomic — R15-proven faster than ballot compact)
#pragma unroll
    for (int s = 0; s < 32; ++s) {
        uint32_t hbA = __float_as_uint(dA[s]);
        if (hbA <= V_A) {
            uint32_t p = atomicAdd(&ccntA, 1u);
            if (p < 64u) cbufA[p] = MKKEY(dA, s);
        }
        uint32_t hbB = __float_as_uint(dB[s]);
        if (hbB <= V_B) {
            uint32_t p = atomicAdd(&ccntB, 1u);
            if (p < 64u) cbufB[p] = MKKEY(dB, s);
        }
    }
#undef MKKEY
    __syncthreads();
    // wave 0 sorts row A, wave 1 sorts row B (proven bitonic-64 network)
    if (w < 2) {
        const uint32_t n = (w == 0) ? (ccntA < 64u ? ccntA : 64u)
                                    : (ccntB < 64u ? ccntB : 64u);
        unsigned long long key =
            ((uint32_t)l < n) ? (w == 0 ? cbufA[l] : cbufB[l]) : ~0ull;
#pragma unroll
        for (int k = 2; k <= 64; k <<= 1) {
            for (int j2 = k >> 1; j2 > 0; j2 >>= 1) {
                unsigned long long o = __shfl_xor(key, j2, 64);
                bool up = ((l & k) == 0);
                bool lower = ((l & j2) == 0);
                unsigned long long mn2 = key < o ? key : o;
                unsigned long long mx = key < o ? o : key;
                key = (up == lower) ? mn2 : mx;
            }
        }
        if (l < KNB)
            edgesT[(size_t)l * TOT + (w == 0 ? rowA : rowB)] =
                (int)(key & 0xffffffffu);
    }
}

// ------- one smoothing step (edgesT[k][row]: coalesced neighbor loads) -------
__global__ void smooth_kernel(const float* __restrict__ zin,
                              float* __restrict__ zout,
                              const int* __restrict__ edgesT,
                              const int* __restrict__ C) {
    int t = blockIdx.x * blockDim.x + threadIdx.x;
    if (t >= TOT) return;
    float acc = 0.0f;
    if (C[t] > 0) {
        const int b = t >> 13;
        const float* zb = zin + (size_t)b * NN;
#pragma unroll
        for (int k = 0; k < KNB; ++k)
            acc = __fadd_rn(acc, zb[edgesT[(size_t)k * TOT + t]]);
        acc = __fdiv_rn(acc, __fadd_rn(30.0f, 1e-5f));
    }
    zout[t] = acc;
}

// ---------------- z += priority; stable ascending argsort per batch ----------
__global__ __launch_bounds__(1024) void sort_kernel(const float* __restrict__ z,
                                                    const float* __restrict__ prio,
                                                    int* __restrict__ out) {
    __shared__ unsigned long long keys[NN];  // 64 KiB
    const int b = blockIdx.x;
    for (int i = threadIdx.x; i < NN; i += 1024) {
        float v = z[(size_t)b * NN + i] + prio[(size_t)b * NN + i];
        uint32_t u = __float_as_uint(v);
        u ^= (u >> 31) ? 0xFFFFFFFFu : 0x80000000u;  // monotonic float->uint
        keys[i] = ((unsigned long long)u << 32) | (unsigned)i;
    }
    __syncthreads();
    for (int k = 2; k <= NN; k <<= 1) {
        for (int j = k >> 1; j > 0; j >>= 1) {
            for (int i = threadIdx.x; i < NN; i += 1024) {
                int ixj = i ^ j;
                if (ixj > i) {
                    unsigned long long a = keys[i], c = keys[ixj];
                    bool up = ((i & k) == 0);
                    if ((a > c) == up) { keys[i] = c; keys[ixj] = a; }
                }
            }
            __syncthreads();
        }
    }
    for (int i = threadIdx.x; i < NN; i += 1024)
        out[(size_t)b * NN + i] = (int)(keys[i] & 0xffffffffu);
}

extern "C" void kernel_launch(void* const* d_in, const int* in_sizes, int n_in,
                              void* d_out, int out_size, void* d_ws, size_t ws_size,
                              hipStream_t stream) {
    const float* X = (const float*)d_in[0];    // [4,8192,3] f32
    const int* C = (const int*)d_in[1];        // [4,8192] int32
    const float* prio = (const float*)d_in[2]; // [4,8192] f32
    int* out = (int*)d_out;                    // [4,8192] i32

    float* z0 = (float*)d_ws;
    float* z1 = z0 + TOT;
    int* edgesT = (int*)(z1 + TOT);            // [KNB][TOT]
    float* Xs = (float*)(edgesT + (size_t)TOT * KNB);  // [NB][3][NN]

    prep_kernel<<<TOT / 256, 256, 0, stream>>>(X, C, z0, Xs);
    knn_kernel<<<TOT / 2, 256, 0, stream>>>(Xs, X, edgesT);

    float* cur = z0;
    float* nxt = z1;
    for (int s = 0; s < 5; ++s) {
        smooth_kernel<<<TOT / 256, 256, 0, stream>>>(cur, nxt, edgesT, C);
        float* tmp = cur; cur = nxt; nxt = tmp;
    }
    sort_kernel<<<NB, 1024, 0, stream>>>(cur, prio, out);
}